// Round 6
// baseline (398.765 us; speedup 1.0000x reference)
//
#include <hip/hip_runtime.h>
#include <hip/hip_bf16.h>

// DECOLLE SNN forward, MI355X. B=32, F_IN=512, H=1024, OUT=128, T=256.
// Round 6: barrier-free MFMA GEMMs — direct global->register fragment loads
// (no LDS, no __syncthreads => compiler emits counted vmcnt, deep overlap),
// 2-plane bf16 weight split (hi+mid, rel err ~2^-17 ~= f32 reorder noise).
// d_out layout (floats): s1[8M] s2[8M] r1[1M] r2[1M] v1[8M] v2[8M] c1 c2

#define S_SZ 8388608
#define R_SZ 1048576

typedef __attribute__((ext_vector_type(8))) short v8s;
typedef __attribute__((ext_vector_type(4))) float v4f;
typedef __attribute__((ext_vector_type(8))) unsigned short u8us;

static __device__ __forceinline__ unsigned short f2bf(float x) {
  union { __hip_bfloat16 b; unsigned short u; } cv;
  cv.b = __float2bfloat16(x);
  return cv.u;
}
static __device__ __forceinline__ float bf2f(unsigned short u) {
  union { __hip_bfloat16 b; unsigned short u; } cv;
  cv.u = u;
  return __bfloat162float(cv.b);
}

// ================= fast path =================

// one launch: split all 4 weight tensors into 2 bf16 planes + zero counters
__global__ __launch_bounds__(256) void split_all_kernel(
    const float* __restrict__ W1, const float* __restrict__ W2,
    const float* __restrict__ R1, const float* __restrict__ R2,
    unsigned short* __restrict__ w1s, unsigned short* __restrict__ w2s,
    unsigned short* __restrict__ r1s, unsigned short* __restrict__ r2s,
    int* __restrict__ cnt) {
  if (blockIdx.y == 0 && blockIdx.x == 0 && threadIdx.x == 0) {
    cnt[0] = 0; cnt[1] = 0;
  }
  const int i = blockIdx.x * 256 + threadIdx.x;
  const float* W; unsigned short* out; int N;
  switch (blockIdx.y) {
    case 0: W = W1; out = w1s; N = 524288; break;
    case 1: W = W2; out = w2s; N = 1048576; break;
    case 2: W = R1; out = r1s; N = 131072; break;
    default: W = R2; out = r2s; N = 131072; break;
  }
  if (i >= N) return;
  const float w0 = W[i];
  const unsigned short h = f2bf(w0);
  const float hf = bf2f(h);
  const unsigned short m = f2bf(w0 - hf);  // w ~= hi + mid, rel err ~2^-17
  out[i] = h; out[N + i] = m;
}

// transpose+convert input spikes: f32 [b][512][256] -> bf16 [b][256][512]
__global__ __launch_bounds__(256) void tcvt_kernel(const float* __restrict__ in,
                                                   unsigned short* __restrict__ out,
                                                   int R) {
  __shared__ float Ls[64][68];
  const int r0 = blockIdx.x * 64, c0 = blockIdx.y * 64, b = blockIdx.z;
  const int tid = threadIdx.x;
  const float* ip = in + ((size_t)b * R + r0) * 256 + c0;
#pragma unroll
  for (int it = 0; it < 4; ++it) {
    const int row = it * 16 + (tid >> 4), col = (tid & 15) * 4;
    const float4 v = *(const float4*)&ip[(size_t)row * 256 + col];
    *(float4*)&Ls[row][col] = v;
  }
  __syncthreads();
  const int c = tid >> 2, rs = (tid & 3) * 16;
  unsigned short h[16];
#pragma unroll
  for (int j = 0; j < 16; ++j) h[j] = f2bf(Ls[rs + j][c]);
  u8us p0, p1;
#pragma unroll
  for (int j = 0; j < 8; ++j) { p0[j] = h[j]; p1[j] = h[8 + j]; }
  unsigned short* op = out + ((size_t)b * 256 + c0 + c) * R + r0 + rs;
  *(u8us*)(op) = p0;
  *(u8us*)(op + 8) = p1;
}

// Z[b][m][t] = sum_s sum_k Asp[s][m][k] * XT[b][t][k]   (bf16 MFMA, f32 acc)
// Barrier-free: all fragments direct global->reg; 4 waves (2m x 2t),
// tile 128m x 64t, 2 batches/block. Loads ordered B, A(s0), A(s1);
// MFMAs s0 then s1 so s0 compute overlaps s1 loads.
__global__ __launch_bounds__(256) void gemm_mfma_reg(
    const unsigned short* __restrict__ Asp,  // [2][M][K] bf16
    const unsigned short* __restrict__ XT,   // [32][256][K] bf16
    float* __restrict__ Z,                   // [32][M][256] f32
    int M, int K) {
  const int t0 = blockIdx.x * 64;
  const int m0 = blockIdx.y * 128;
  const int bg = blockIdx.z;
  const int tid = threadIdx.x;
  const int w = tid >> 6, lane = tid & 63;
  const int r = lane & 15, q = lane >> 4;
  const int wm = w >> 1, wt = w & 1;
  const size_t MK = (size_t)M * K;
  const int nkc = K >> 6;

  v4f acc[2][4][2];
#pragma unroll
  for (int ib = 0; ib < 2; ++ib)
#pragma unroll
    for (int f = 0; f < 4; ++f)
#pragma unroll
      for (int g = 0; g < 2; ++g) acc[ib][f][g] = (v4f){0.f, 0.f, 0.f, 0.f};

  // per-lane base pointers (fragment element k = k0 + ks*32 + q*8 + j)
  const unsigned short* aB = Asp + (size_t)(m0 + wm * 64 + r) * K + q * 8;
  const unsigned short* bB0 =
      XT + ((size_t)(bg * 2 + 0) * 256 + t0 + wt * 32 + r) * K + q * 8;
  const unsigned short* bB1 =
      XT + ((size_t)(bg * 2 + 1) * 256 + t0 + wt * 32 + r) * K + q * 8;

  for (int kc = 0; kc < nkc; ++kc) {
    const int k0 = kc << 6;
    v8s b[2][2][2];  // [ib][ks][g]
#pragma unroll
    for (int ks = 0; ks < 2; ++ks)
#pragma unroll
      for (int g = 0; g < 2; ++g) {
        b[0][ks][g] = *(const v8s*)(bB0 + (size_t)(g * 16) * K + k0 + ks * 32);
        b[1][ks][g] = *(const v8s*)(bB1 + (size_t)(g * 16) * K + k0 + ks * 32);
      }
    v8s a[2][4][2];  // [s][f][ks]
#pragma unroll
    for (int s = 0; s < 2; ++s)
#pragma unroll
      for (int f = 0; f < 4; ++f)
#pragma unroll
        for (int ks = 0; ks < 2; ++ks)
          a[s][f][ks] =
              *(const v8s*)(aB + s * MK + (size_t)(f * 16) * K + k0 + ks * 32);
#pragma unroll
    for (int s = 0; s < 2; ++s)
#pragma unroll
      for (int ks = 0; ks < 2; ++ks)
#pragma unroll
        for (int f = 0; f < 4; ++f)
#pragma unroll
          for (int ib = 0; ib < 2; ++ib) {
            acc[ib][f][0] = __builtin_amdgcn_mfma_f32_16x16x32_bf16(
                a[s][f][ks], b[ib][ks][0], acc[ib][f][0], 0, 0, 0);
            acc[ib][f][1] = __builtin_amdgcn_mfma_f32_16x16x32_bf16(
                a[s][f][ks], b[ib][ks][1], acc[ib][f][1], 0, 0, 0);
          }
  }

  // epilogue: C/D map col=lane&15 (t), row=q*4+e (m)  [m89-verified]
#pragma unroll
  for (int ib = 0; ib < 2; ++ib) {
    float* Zb = Z + ((size_t)(bg * 2 + ib) * M) * 256;
#pragma unroll
    for (int f = 0; f < 4; ++f)
#pragma unroll
      for (int g = 0; g < 2; ++g)
#pragma unroll
        for (int e = 0; e < 4; ++e)
          Zb[(size_t)(m0 + wm * 64 + f * 16 + q * 4 + e) * 256 +
             t0 + wt * 32 + g * 16 + r] = acc[ib][f][g][e];
  }
}

// readouts: O[b][o][t] = sum_s sum_k Rsp[s][o][k] * ST[b][t][k]; M=128, K=1024
// grid (4 t-tiles, 2 nets, 32 b); barrier-free reg fragments; counts fused.
__global__ __launch_bounds__(256) void readout_mfma_reg(
    const unsigned short* __restrict__ r1s, const unsigned short* __restrict__ r2s,
    const unsigned short* __restrict__ s1T, const unsigned short* __restrict__ s2T,
    float* __restrict__ O1, float* __restrict__ O2,
    const int* __restrict__ cnt, float* __restrict__ cc) {
  if (blockIdx.x == 0 && blockIdx.y == 0 && blockIdx.z == 0 && threadIdx.x == 0) {
    cc[0] = (float)cnt[0] * (1.0f / 8388608.0f);
    cc[1] = (float)cnt[1] * (1.0f / 8388608.0f);
  }
  const int K = 1024;
  const int t0 = blockIdx.x * 64;
  const int net = blockIdx.y;
  const int b = blockIdx.z;
  const unsigned short* __restrict__ Asp = net ? r2s : r1s;
  const unsigned short* __restrict__ XT = (net ? s2T : s1T) + (size_t)b * 256 * K;
  float* __restrict__ Zb = (net ? O2 : O1) + (size_t)b * 128 * 256;

  const int tid = threadIdx.x;
  const int w = tid >> 6, lane = tid & 63;
  const int r = lane & 15, q = lane >> 4;
  const int wm = w >> 1, wt = w & 1;
  const size_t MK = (size_t)128 * K;

  v4f acc[4][2];
#pragma unroll
  for (int f = 0; f < 4; ++f)
#pragma unroll
    for (int g = 0; g < 2; ++g) acc[f][g] = (v4f){0.f, 0.f, 0.f, 0.f};

  const unsigned short* aB = Asp + (size_t)(wm * 64 + r) * K + q * 8;
  const unsigned short* bB = XT + (size_t)(t0 + wt * 32 + r) * K + q * 8;

  for (int kc = 0; kc < 16; ++kc) {
    const int k0 = kc << 6;
    v8s b[2][2];  // [ks][g]
#pragma unroll
    for (int ks = 0; ks < 2; ++ks)
#pragma unroll
      for (int g = 0; g < 2; ++g)
        b[ks][g] = *(const v8s*)(bB + (size_t)(g * 16) * K + k0 + ks * 32);
    v8s a[2][4][2];  // [s][f][ks]
#pragma unroll
    for (int s = 0; s < 2; ++s)
#pragma unroll
      for (int f = 0; f < 4; ++f)
#pragma unroll
        for (int ks = 0; ks < 2; ++ks)
          a[s][f][ks] =
              *(const v8s*)(aB + s * MK + (size_t)(f * 16) * K + k0 + ks * 32);
#pragma unroll
    for (int s = 0; s < 2; ++s)
#pragma unroll
      for (int ks = 0; ks < 2; ++ks)
#pragma unroll
        for (int f = 0; f < 4; ++f) {
          acc[f][0] = __builtin_amdgcn_mfma_f32_16x16x32_bf16(
              a[s][f][ks], b[ks][0], acc[f][0], 0, 0, 0);
          acc[f][1] = __builtin_amdgcn_mfma_f32_16x16x32_bf16(
              a[s][f][ks], b[ks][1], acc[f][1], 0, 0, 0);
        }
  }

#pragma unroll
  for (int f = 0; f < 4; ++f)
#pragma unroll
    for (int g = 0; g < 2; ++g)
#pragma unroll
      for (int e = 0; e < 4; ++e)
        Zb[(size_t)(wm * 64 + f * 16 + q * 4 + e) * 256 +
           t0 + wt * 32 + g * 16 + r] = acc[f][g][e];
}

// ================= CUBA scan =================
// in-place z->v, f32 spikes to S, bf16 transposed spikes to ST[b][t][h] (h=1024).
// 4-chunk-deep prefetch ring, fully unrolled (static indices only).
__global__ __launch_bounds__(64) void scan_kernel(float* __restrict__ VZ,
                                                  float* __restrict__ S,
                                                  unsigned short* __restrict__ ST,
                                                  int* __restrict__ cnt) {
  const int g = blockIdx.x * 64 + threadIdx.x;  // (b,h) row
  float* vz = VZ + (size_t)g * 256;
  float* sp = S + (size_t)g * 256;
  unsigned short* st =
      ST ? ST + ((size_t)(g >> 10) * 256) * 1024 + (g & 1023) : nullptr;
  const float CD = 0.75f;
  const float VD = (float)(1.0 - 0.03);

  float4 buf[4][4];
#pragma unroll
  for (int i = 0; i < 4; ++i)
#pragma unroll
    for (int qq = 0; qq < 4; ++qq)
      buf[i][qq] = *(const float4*)(vz + i * 16 + qq * 4);

  float cur = 0.f, volt = 0.f;
  int c = 0;
#pragma unroll
  for (int tc = 0; tc < 16; ++tc) {
    float zv[16];
    *(float4*)&zv[0]  = buf[tc & 3][0];
    *(float4*)&zv[4]  = buf[tc & 3][1];
    *(float4*)&zv[8]  = buf[tc & 3][2];
    *(float4*)&zv[12] = buf[tc & 3][3];
    if (tc < 12) {
#pragma unroll
      for (int qq = 0; qq < 4; ++qq)
        buf[tc & 3][qq] = *(const float4*)(vz + (tc + 4) * 16 + qq * 4);
    }
    float vv[16], sv[16];
    unsigned short sb[16];
#pragma unroll
    for (int j = 0; j < 16; ++j) {
      cur = CD * cur + zv[j];
      volt = VD * volt + cur;
      vv[j] = volt;  // pre-reset voltage
      const bool spk = volt >= 1.25f;
      sv[j] = spk ? 1.0f : 0.0f;
      sb[j] = spk ? 0x3F80 : 0;  // bf16(1.0) / bf16(0.0)
      c += spk ? 1 : 0;
      volt = spk ? 0.f : volt;
    }
    float4 o;
    o = {vv[0], vv[1], vv[2], vv[3]};     *(float4*)(vz + tc * 16 + 0) = o;
    o = {vv[4], vv[5], vv[6], vv[7]};     *(float4*)(vz + tc * 16 + 4) = o;
    o = {vv[8], vv[9], vv[10], vv[11]};   *(float4*)(vz + tc * 16 + 8) = o;
    o = {vv[12], vv[13], vv[14], vv[15]}; *(float4*)(vz + tc * 16 + 12) = o;
    o = {sv[0], sv[1], sv[2], sv[3]};     *(float4*)(sp + tc * 16 + 0) = o;
    o = {sv[4], sv[5], sv[6], sv[7]};     *(float4*)(sp + tc * 16 + 4) = o;
    o = {sv[8], sv[9], sv[10], sv[11]};   *(float4*)(sp + tc * 16 + 8) = o;
    o = {sv[12], sv[13], sv[14], sv[15]}; *(float4*)(sp + tc * 16 + 12) = o;
    if (st) {
#pragma unroll
      for (int j = 0; j < 16; ++j)
        st[(size_t)(tc * 16 + j) * 1024] = sb[j];
    }
  }
#pragma unroll
  for (int off = 32; off > 0; off >>= 1) c += __shfl_down(c, off);
  if (threadIdx.x == 0) atomicAdd(cnt, c);
}

__global__ void finalize_kernel(const int* __restrict__ cnt, float* __restrict__ c) {
  if (threadIdx.x == 0) {
    c[0] = (float)cnt[0] * (1.0f / 8388608.0f);
    c[1] = (float)cnt[1] * (1.0f / 8388608.0f);
  }
}

// ================= fallback path (round-1 f32 kernels) =================

__global__ __launch_bounds__(256) void zero_r_kernel(float* __restrict__ r,
                                                     int* __restrict__ cnt) {
  int i = blockIdx.x * 256 + threadIdx.x;
  float4 z{0.f, 0.f, 0.f, 0.f};
  *(float4*)&r[(size_t)i * 4] = z;
  if (i == 0) { cnt[0] = 0; cnt[1] = 0; }
}

__global__ __launch_bounds__(256) void gemm_f32(
    const float* __restrict__ W, const float* __restrict__ X,
    float* __restrict__ Z, int M, int K) {
  const int T = 256;
  const int tt0 = blockIdx.x * 64;
  const int m0 = blockIdx.y * 128;
  const int b = blockIdx.z;
  const float* __restrict__ Xb = X + (size_t)b * K * T;
  float* __restrict__ Zb = Z + (size_t)b * M * T;
  __shared__ float Ws[16][132];
  __shared__ float Xs[16][68];
  const int tid = threadIdx.x;
  const int tx = tid & 15, ty = tid >> 4;
  const int ah = tid >> 1, ac = (tid & 1) * 8;
  const int bf = tid >> 4, btq = (tid & 15) * 4;
  float acc[8][4];
#pragma unroll
  for (int i = 0; i < 8; ++i)
#pragma unroll
    for (int j = 0; j < 4; ++j) acc[i][j] = 0.f;
  const float* wp = &W[(size_t)(m0 + ah) * K + ac];
  const float* xp = &Xb[(size_t)bf * T + tt0 + btq];
  for (int k0 = 0; k0 < K; k0 += 16) {
    float4 wa0 = *(const float4*)(wp + k0);
    float4 wa1 = *(const float4*)(wp + k0 + 4);
    float4 xv = *(const float4*)(xp + (size_t)k0 * T);
    __syncthreads();
    Ws[ac + 0][ah] = wa0.x; Ws[ac + 1][ah] = wa0.y;
    Ws[ac + 2][ah] = wa0.z; Ws[ac + 3][ah] = wa0.w;
    Ws[ac + 4][ah] = wa1.x; Ws[ac + 5][ah] = wa1.y;
    Ws[ac + 6][ah] = wa1.z; Ws[ac + 7][ah] = wa1.w;
    *(float4*)&Xs[bf][btq] = xv;
    __syncthreads();
#pragma unroll
    for (int f = 0; f < 16; ++f) {
      float4 a0 = *(const float4*)&Ws[f][ty * 8];
      float4 a1 = *(const float4*)&Ws[f][ty * 8 + 4];
      float4 xr = *(const float4*)&Xs[f][tx * 4];
      float av[8] = {a0.x, a0.y, a0.z, a0.w, a1.x, a1.y, a1.z, a1.w};
      float xw[4] = {xr.x, xr.y, xr.z, xr.w};
#pragma unroll
      for (int i = 0; i < 8; ++i)
#pragma unroll
        for (int j = 0; j < 4; ++j) acc[i][j] = fmaf(av[i], xw[j], acc[i][j]);
    }
  }
#pragma unroll
  for (int i = 0; i < 8; ++i) {
    float4 o{acc[i][0], acc[i][1], acc[i][2], acc[i][3]};
    *(float4*)&Zb[(size_t)(m0 + ty * 8 + i) * T + tt0 + tx * 4] = o;
  }
}

__global__ __launch_bounds__(256) void readout_kernel(
    const float* __restrict__ R1, const float* __restrict__ R2,
    const float* __restrict__ S1, const float* __restrict__ S2,
    float* __restrict__ O1, float* __restrict__ O2) {
  const int T = 256, K = 1024;
  const int tt0 = blockIdx.x * 64;
  const int kbeg = blockIdx.y * 256;
  const int zz = blockIdx.z;
  const int b = zz & 31;
  const float* __restrict__ R = (zz < 32) ? R1 : R2;
  const float* __restrict__ Sb = ((zz < 32) ? S1 : S2) + (size_t)b * K * T;
  float* __restrict__ Ob = ((zz < 32) ? O1 : O2) + (size_t)b * 128 * T;
  __shared__ float Ws[16][132];
  __shared__ float Xs[16][68];
  const int tid = threadIdx.x;
  const int tx = tid & 15, ty = tid >> 4;
  const int ah = tid >> 1, ac = (tid & 1) * 8;
  const int bf = tid >> 4, btq = (tid & 15) * 4;
  float acc[8][4];
#pragma unroll
  for (int i = 0; i < 8; ++i)
#pragma unroll
    for (int j = 0; j < 4; ++j) acc[i][j] = 0.f;
  const float* wp = &R[(size_t)ah * K + ac];
  const float* xp = &Sb[(size_t)bf * T + tt0 + btq];
  for (int k0 = kbeg; k0 < kbeg + 256; k0 += 16) {
    float4 wa0 = *(const float4*)(wp + k0);
    float4 wa1 = *(const float4*)(wp + k0 + 4);
    float4 xv = *(const float4*)(xp + (size_t)k0 * T);
    __syncthreads();
    Ws[ac + 0][ah] = wa0.x; Ws[ac + 1][ah] = wa0.y;
    Ws[ac + 2][ah] = wa0.z; Ws[ac + 3][ah] = wa0.w;
    Ws[ac + 4][ah] = wa1.x; Ws[ac + 5][ah] = wa1.y;
    Ws[ac + 6][ah] = wa1.z; Ws[ac + 7][ah] = wa1.w;
    *(float4*)&Xs[bf][btq] = xv;
    __syncthreads();
#pragma unroll
    for (int f = 0; f < 16; ++f) {
      float4 a0 = *(const float4*)&Ws[f][ty * 8];
      float4 a1 = *(const float4*)&Ws[f][ty * 8 + 4];
      float4 xr = *(const float4*)&Xs[f][tx * 4];
      float av[8] = {a0.x, a0.y, a0.z, a0.w, a1.x, a1.y, a1.z, a1.w};
      float xw[4] = {xr.x, xr.y, xr.z, xr.w};
#pragma unroll
      for (int i = 0; i < 8; ++i)
#pragma unroll
        for (int j = 0; j < 4; ++j) acc[i][j] = fmaf(av[i], xw[j], acc[i][j]);
    }
  }
#pragma unroll
  for (int i = 0; i < 8; ++i)
#pragma unroll
    for (int j = 0; j < 4; ++j)
      atomicAdd(&Ob[(size_t)(ty * 8 + i) * T + tt0 + tx * 4 + j], acc[i][j]);
}

// ================= launch =================
extern "C" void kernel_launch(void* const* d_in, const int* in_sizes, int n_in,
                              void* d_out, int out_size, void* d_ws, size_t ws_size,
                              hipStream_t stream) {
  const float* spike = (const float*)d_in[0];
  const float* W1 = (const float*)d_in[1];
  const float* W2 = (const float*)d_in[2];
  const float* R1 = (const float*)d_in[3];
  const float* R2 = (const float*)d_in[4];

  float* out = (float*)d_out;
  float* s1 = out;
  float* s2 = out + S_SZ;
  float* r1 = out + 2 * S_SZ;
  float* r2 = out + 2 * S_SZ + R_SZ;
  float* v1 = out + 2 * S_SZ + 2 * R_SZ;  // z1 then v1, in place
  float* v2 = out + 2 * S_SZ + 2 * R_SZ + S_SZ;
  float* cc = out + 4 * S_SZ + 2 * R_SZ;

  int* cnt = (int*)d_ws;
  unsigned short* w1s = (unsigned short*)((char*)d_ws + 64);  // 2 planes each
  unsigned short* w2s = w1s + 2 * 524288;
  unsigned short* r1s = w2s + 2 * 1048576;
  unsigned short* r2s = r1s + 2 * 131072;
  unsigned short* xT  = r2s + 2 * 131072;
  unsigned short* s1T = xT + 4194304;
  unsigned short* s2T = s1T + 8388608;
  const size_t WS_NEED = 48000000;  // 47.4 MB rounded up

  if (ws_size >= WS_NEED) {
    split_all_kernel<<<dim3(4096, 4), 256, 0, stream>>>(W1, W2, R1, R2, w1s, w2s,
                                                        r1s, r2s, cnt);
    tcvt_kernel<<<dim3(8, 4, 32), 256, 0, stream>>>(spike, xT, 512);
    gemm_mfma_reg<<<dim3(4, 8, 16), 256, 0, stream>>>(w1s, xT, v1, 1024, 512);
    scan_kernel<<<512, 64, 0, stream>>>(v1, s1, s1T, cnt + 0);
    gemm_mfma_reg<<<dim3(4, 8, 16), 256, 0, stream>>>(w2s, s1T, v2, 1024, 1024);
    scan_kernel<<<512, 64, 0, stream>>>(v2, s2, s2T, cnt + 1);
    readout_mfma_reg<<<dim3(4, 2, 32), 256, 0, stream>>>(r1s, r2s, s1T, s2T, r1,
                                                         r2, cnt, cc);
  } else {
    zero_r_kernel<<<2048, 256, 0, stream>>>(r1, cnt);
    gemm_f32<<<dim3(4, 8, 32), 256, 0, stream>>>(W1, spike, v1, 1024, 512);
    scan_kernel<<<512, 64, 0, stream>>>(v1, s1, nullptr, cnt + 0);
    gemm_f32<<<dim3(4, 8, 32), 256, 0, stream>>>(W2, s1, v2, 1024, 1024);
    scan_kernel<<<512, 64, 0, stream>>>(v2, s2, nullptr, cnt + 1);
    readout_kernel<<<dim3(4, 4, 64), 256, 0, stream>>>(R1, R2, s1, s2, r1, r2);
    finalize_kernel<<<1, 1, 0, stream>>>(cnt, cc);
  }
}

// Round 7
// 328.901 us; speedup vs baseline: 1.2124x; 1.2124x over previous
//
#include <hip/hip_runtime.h>
#include <hip/hip_bf16.h>

// DECOLLE SNN forward, MI355X. B=32, F_IN=512, H=1024, OUT=128, T=256.
// Round 7: LDS-A (global_load_lds, deduped, dbuf) + reg-B prefetch,
// 2-plane bf16 split, 1 batch/block (1024 blocks = 4/CU = 16 waves/CU,
// __launch_bounds__(256,4) caps VGPR at 128). Readout at t=32 (512 blocks).
// d_out layout (floats): s1[8M] s2[8M] r1[1M] r2[1M] v1[8M] v2[8M] c1 c2

#define S_SZ 8388608
#define R_SZ 1048576

typedef __attribute__((ext_vector_type(8))) short v8s;
typedef __attribute__((ext_vector_type(4))) float v4f;
typedef __attribute__((ext_vector_type(8))) unsigned short u8us;

static __device__ __forceinline__ unsigned short f2bf(float x) {
  union { __hip_bfloat16 b; unsigned short u; } cv;
  cv.b = __float2bfloat16(x);
  return cv.u;
}
static __device__ __forceinline__ float bf2f(unsigned short u) {
  union { __hip_bfloat16 b; unsigned short u; } cv;
  cv.u = u;
  return __bfloat162float(cv.b);
}

// ================= fast path =================

// one launch: split all 4 weight tensors into 2 bf16 planes + zero counters
__global__ __launch_bounds__(256) void split_all_kernel(
    const float* __restrict__ W1, const float* __restrict__ W2,
    const float* __restrict__ R1, const float* __restrict__ R2,
    unsigned short* __restrict__ w1s, unsigned short* __restrict__ w2s,
    unsigned short* __restrict__ r1s, unsigned short* __restrict__ r2s,
    int* __restrict__ cnt) {
  if (blockIdx.y == 0 && blockIdx.x == 0 && threadIdx.x == 0) {
    cnt[0] = 0; cnt[1] = 0;
  }
  const int i = blockIdx.x * 256 + threadIdx.x;
  const float* W; unsigned short* out; int N;
  switch (blockIdx.y) {
    case 0: W = W1; out = w1s; N = 524288; break;
    case 1: W = W2; out = w2s; N = 1048576; break;
    case 2: W = R1; out = r1s; N = 131072; break;
    default: W = R2; out = r2s; N = 131072; break;
  }
  if (i >= N) return;
  const float w0 = W[i];
  const unsigned short h = f2bf(w0);
  const float hf = bf2f(h);
  const unsigned short m = f2bf(w0 - hf);  // w ~= hi + mid, rel err ~2^-17
  out[i] = h; out[N + i] = m;
}

// transpose+convert input spikes: f32 [b][512][256] -> bf16 [b][256][512]
__global__ __launch_bounds__(256) void tcvt_kernel(const float* __restrict__ in,
                                                   unsigned short* __restrict__ out,
                                                   int R) {
  __shared__ float Ls[64][68];
  const int r0 = blockIdx.x * 64, c0 = blockIdx.y * 64, b = blockIdx.z;
  const int tid = threadIdx.x;
  const float* ip = in + ((size_t)b * R + r0) * 256 + c0;
#pragma unroll
  for (int it = 0; it < 4; ++it) {
    const int row = it * 16 + (tid >> 4), col = (tid & 15) * 4;
    const float4 v = *(const float4*)&ip[(size_t)row * 256 + col];
    *(float4*)&Ls[row][col] = v;
  }
  __syncthreads();
  const int c = tid >> 2, rs = (tid & 3) * 16;
  unsigned short h[16];
#pragma unroll
  for (int j = 0; j < 16; ++j) h[j] = f2bf(Ls[rs + j][c]);
  u8us p0, p1;
#pragma unroll
  for (int j = 0; j < 8; ++j) { p0[j] = h[j]; p1[j] = h[8 + j]; }
  unsigned short* op = out + ((size_t)b * 256 + c0 + c) * R + r0 + rs;
  *(u8us*)(op) = p0;
  *(u8us*)(op + 8) = p1;
}

// Z[b][m][t] = sum_s sum_k Asp[s][m][k] * XT[b][t][k]   (bf16 MFMA, f32 acc)
// A: global_load_lds into dbuf 2x16KB (XOR-swizzled source, linear dest);
// B: register fragments, ping-pong prefetch. 4 waves (2m x 2t), 128m x 64t,
// 1 batch/block. 4 phases per 2 K-chunks; one __syncthreads per phase;
// 4 blocks/CU so barrier drains overlap across blocks.
__global__ __launch_bounds__(256, 4) void gemm_mfma_lds(
    const unsigned short* __restrict__ Asp,  // [2][M][K] bf16
    const unsigned short* __restrict__ XT,   // [32][256][K] bf16
    float* __restrict__ Z,                   // [32][M][256] f32
    int M, int K) {
  __shared__ unsigned short Alds[2][128 * 64];  // 2 x 16 KB
  const int t0 = blockIdx.x * 64;
  const int m0 = blockIdx.y * 128;
  const int b = blockIdx.z;
  const int tid = threadIdx.x;
  const int w = tid >> 6, lane = tid & 63;
  const int r = lane & 15, q = lane >> 4;
  const int wm = w >> 1, wt = w & 1;
  const int srow = lane >> 3, sslot = lane & 7;
  const size_t MK = (size_t)M * K;
  const int nkc = K >> 6;  // even for all our K

  v4f acc[4][2];
#pragma unroll
  for (int f = 0; f < 4; ++f)
#pragma unroll
    for (int g = 0; g < 2; ++g) acc[f][g] = (v4f){0.f, 0.f, 0.f, 0.f};

  auto STAGE = [&](int buf, int s, int kc) {
    const int k0 = kc << 6;
#pragma unroll
    for (int c = 0; c < 4; ++c) {
      const int row = w * 32 + c * 8 + srow;
      const unsigned short* src = Asp + (size_t)s * MK + (size_t)(m0 + row) * K +
                                  k0 + ((sslot ^ (row & 7)) << 3);
      unsigned short* dst = &Alds[buf][(w * 32 + c * 8) * 64];
      __builtin_amdgcn_global_load_lds(
          (const __attribute__((address_space(1))) unsigned int*)src,
          (__attribute__((address_space(3))) unsigned int*)dst, 16, 0, 0);
    }
  };
  const unsigned short* bBase =
      XT + ((size_t)b * 256 + t0 + wt * 32 + r) * K + q * 8;
  auto BLOAD = [&](v8s (&bfr)[2][2], int kc) {
    const int k0 = kc << 6;
#pragma unroll
    for (int ks = 0; ks < 2; ++ks)
#pragma unroll
      for (int g = 0; g < 2; ++g)
        bfr[ks][g] = *(const v8s*)(bBase + (size_t)(g * 16) * K + k0 + ks * 32);
  };
  auto COMPUTE = [&](int buf, v8s (&bfr)[2][2]) {
#pragma unroll
    for (int ks = 0; ks < 2; ++ks)
#pragma unroll
      for (int f = 0; f < 4; ++f) {
        const int arow = wm * 64 + f * 16 + r;
        const v8s a = *(const v8s*)&Alds[buf][arow * 64 +
                                             (((ks * 4 + q) ^ (arow & 7)) << 3)];
        acc[f][0] = __builtin_amdgcn_mfma_f32_16x16x32_bf16(
            a, bfr[ks][0], acc[f][0], 0, 0, 0);
        acc[f][1] = __builtin_amdgcn_mfma_f32_16x16x32_bf16(
            a, bfr[ks][1], acc[f][1], 0, 0, 0);
      }
  };

  v8s bA[2][2], bB[2][2];
  STAGE(0, 0, 0);
  BLOAD(bA, 0);
  __syncthreads();
  int buf = 0;
  for (int kc = 0; kc < nkc; kc += 2) {
    STAGE(buf ^ 1, 1, kc);                          // plane 1 of kc
    COMPUTE(buf, bA); __syncthreads(); buf ^= 1;    // plane 0 x bA
    STAGE(buf ^ 1, 0, kc + 1); BLOAD(bB, kc + 1);   // plane 0 of kc+1
    COMPUTE(buf, bA); __syncthreads(); buf ^= 1;    // plane 1 x bA
    STAGE(buf ^ 1, 1, kc + 1);                      // plane 1 of kc+1
    COMPUTE(buf, bB); __syncthreads(); buf ^= 1;    // plane 0 x bB
    if (kc + 2 < nkc) { STAGE(buf ^ 1, 0, kc + 2); BLOAD(bA, kc + 2); }
    COMPUTE(buf, bB); __syncthreads(); buf ^= 1;    // plane 1 x bB
  }

  // epilogue: C/D map col=lane&15 (t), row=q*4+e (m)  [m89-verified]
  float* Zb = Z + (size_t)b * M * 256;
#pragma unroll
  for (int f = 0; f < 4; ++f)
#pragma unroll
    for (int g = 0; g < 2; ++g)
#pragma unroll
      for (int e = 0; e < 4; ++e)
        Zb[(size_t)(m0 + wm * 64 + f * 16 + q * 4 + e) * 256 +
           t0 + wt * 32 + g * 16 + r] = acc[f][g][e];
}

// readouts: O[b][o][t] = sum_s sum_k Rsp[s][o][k] * ST[b][t][k]; M=128, K=1024
// Same skeleton, t-tile 32 (waves 2m x 2t -> wave 64m x 16t, g=1),
// grid (8 t, 2 nets, 32 b) = 512 blocks; counts fused.
__global__ __launch_bounds__(256, 4) void readout_mfma_lds(
    const unsigned short* __restrict__ r1s, const unsigned short* __restrict__ r2s,
    const unsigned short* __restrict__ s1T, const unsigned short* __restrict__ s2T,
    float* __restrict__ O1, float* __restrict__ O2,
    const int* __restrict__ cnt, float* __restrict__ cc) {
  if (blockIdx.x == 0 && blockIdx.y == 0 && blockIdx.z == 0 && threadIdx.x == 0) {
    cc[0] = (float)cnt[0] * (1.0f / 8388608.0f);
    cc[1] = (float)cnt[1] * (1.0f / 8388608.0f);
  }
  const int K = 1024;
  const int t0 = blockIdx.x * 32;
  const int net = blockIdx.y;
  const int b = blockIdx.z;
  const unsigned short* __restrict__ Asp = net ? r2s : r1s;
  const unsigned short* __restrict__ XT = (net ? s2T : s1T) + (size_t)b * 256 * K;
  float* __restrict__ Zb = (net ? O2 : O1) + (size_t)b * 128 * 256;

  __shared__ unsigned short Alds[2][128 * 64];
  const int tid = threadIdx.x;
  const int w = tid >> 6, lane = tid & 63;
  const int r = lane & 15, q = lane >> 4;
  const int wm = w >> 1, wt = w & 1;
  const int srow = lane >> 3, sslot = lane & 7;
  const size_t MK = (size_t)128 * K;
  const int nkc = 16;

  v4f acc[4];
#pragma unroll
  for (int f = 0; f < 4; ++f) acc[f] = (v4f){0.f, 0.f, 0.f, 0.f};

  auto STAGE = [&](int buf, int s, int kc) {
    const int k0 = kc << 6;
#pragma unroll
    for (int c = 0; c < 4; ++c) {
      const int row = w * 32 + c * 8 + srow;
      const unsigned short* src = Asp + (size_t)s * MK + (size_t)row * K +
                                  k0 + ((sslot ^ (row & 7)) << 3);
      unsigned short* dst = &Alds[buf][(w * 32 + c * 8) * 64];
      __builtin_amdgcn_global_load_lds(
          (const __attribute__((address_space(1))) unsigned int*)src,
          (__attribute__((address_space(3))) unsigned int*)dst, 16, 0, 0);
    }
  };
  const unsigned short* bBase = XT + (size_t)(t0 + wt * 16 + r) * K + q * 8;
  auto BLOAD = [&](v8s (&bfr)[2], int kc) {
    const int k0 = kc << 6;
#pragma unroll
    for (int ks = 0; ks < 2; ++ks)
      bfr[ks] = *(const v8s*)(bBase + k0 + ks * 32);
  };
  auto COMPUTE = [&](int buf, v8s (&bfr)[2]) {
#pragma unroll
    for (int ks = 0; ks < 2; ++ks)
#pragma unroll
      for (int f = 0; f < 4; ++f) {
        const int arow = wm * 64 + f * 16 + r;
        const v8s a = *(const v8s*)&Alds[buf][arow * 64 +
                                             (((ks * 4 + q) ^ (arow & 7)) << 3)];
        acc[f] = __builtin_amdgcn_mfma_f32_16x16x32_bf16(a, bfr[ks], acc[f],
                                                         0, 0, 0);
      }
  };

  v8s bA[2], bB[2];
  STAGE(0, 0, 0);
  BLOAD(bA, 0);
  __syncthreads();
  int buf = 0;
  for (int kc = 0; kc < nkc; kc += 2) {
    STAGE(buf ^ 1, 1, kc);
    COMPUTE(buf, bA); __syncthreads(); buf ^= 1;
    STAGE(buf ^ 1, 0, kc + 1); BLOAD(bB, kc + 1);
    COMPUTE(buf, bA); __syncthreads(); buf ^= 1;
    STAGE(buf ^ 1, 1, kc + 1);
    COMPUTE(buf, bB); __syncthreads(); buf ^= 1;
    if (kc + 2 < nkc) { STAGE(buf ^ 1, 0, kc + 2); BLOAD(bA, kc + 2); }
    COMPUTE(buf, bB); __syncthreads(); buf ^= 1;
  }

#pragma unroll
  for (int f = 0; f < 4; ++f)
#pragma unroll
    for (int e = 0; e < 4; ++e)
      Zb[(size_t)(wm * 64 + f * 16 + q * 4 + e) * 256 + t0 + wt * 16 + r] =
          acc[f][e];
}

// ================= CUBA scan =================
// in-place z->v, f32 spikes to S, bf16 transposed spikes to ST[b][t][h] (h=1024).
// 4-chunk-deep prefetch ring, fully unrolled (static indices only).
__global__ __launch_bounds__(64) void scan_kernel(float* __restrict__ VZ,
                                                  float* __restrict__ S,
                                                  unsigned short* __restrict__ ST,
                                                  int* __restrict__ cnt) {
  const int g = blockIdx.x * 64 + threadIdx.x;  // (b,h) row
  float* vz = VZ + (size_t)g * 256;
  float* sp = S + (size_t)g * 256;
  unsigned short* st =
      ST ? ST + ((size_t)(g >> 10) * 256) * 1024 + (g & 1023) : nullptr;
  const float CD = 0.75f;
  const float VD = (float)(1.0 - 0.03);

  float4 buf[4][4];
#pragma unroll
  for (int i = 0; i < 4; ++i)
#pragma unroll
    for (int qq = 0; qq < 4; ++qq)
      buf[i][qq] = *(const float4*)(vz + i * 16 + qq * 4);

  float cur = 0.f, volt = 0.f;
  int c = 0;
#pragma unroll
  for (int tc = 0; tc < 16; ++tc) {
    float zv[16];
    *(float4*)&zv[0]  = buf[tc & 3][0];
    *(float4*)&zv[4]  = buf[tc & 3][1];
    *(float4*)&zv[8]  = buf[tc & 3][2];
    *(float4*)&zv[12] = buf[tc & 3][3];
    if (tc < 12) {
#pragma unroll
      for (int qq = 0; qq < 4; ++qq)
        buf[tc & 3][qq] = *(const float4*)(vz + (tc + 4) * 16 + qq * 4);
    }
    float vv[16], sv[16];
    unsigned short sb[16];
#pragma unroll
    for (int j = 0; j < 16; ++j) {
      cur = CD * cur + zv[j];
      volt = VD * volt + cur;
      vv[j] = volt;  // pre-reset voltage
      const bool spk = volt >= 1.25f;
      sv[j] = spk ? 1.0f : 0.0f;
      sb[j] = spk ? 0x3F80 : 0;  // bf16(1.0) / bf16(0.0)
      c += spk ? 1 : 0;
      volt = spk ? 0.f : volt;
    }
    float4 o;
    o = {vv[0], vv[1], vv[2], vv[3]};     *(float4*)(vz + tc * 16 + 0) = o;
    o = {vv[4], vv[5], vv[6], vv[7]};     *(float4*)(vz + tc * 16 + 4) = o;
    o = {vv[8], vv[9], vv[10], vv[11]};   *(float4*)(vz + tc * 16 + 8) = o;
    o = {vv[12], vv[13], vv[14], vv[15]}; *(float4*)(vz + tc * 16 + 12) = o;
    o = {sv[0], sv[1], sv[2], sv[3]};     *(float4*)(sp + tc * 16 + 0) = o;
    o = {sv[4], sv[5], sv[6], sv[7]};     *(float4*)(sp + tc * 16 + 4) = o;
    o = {sv[8], sv[9], sv[10], sv[11]};   *(float4*)(sp + tc * 16 + 8) = o;
    o = {sv[12], sv[13], sv[14], sv[15]}; *(float4*)(sp + tc * 16 + 12) = o;
    if (st) {
#pragma unroll
      for (int j = 0; j < 16; ++j)
        st[(size_t)(tc * 16 + j) * 1024] = sb[j];
    }
  }
#pragma unroll
  for (int off = 32; off > 0; off >>= 1) c += __shfl_down(c, off);
  if (threadIdx.x == 0) atomicAdd(cnt, c);
}

__global__ void finalize_kernel(const int* __restrict__ cnt, float* __restrict__ c) {
  if (threadIdx.x == 0) {
    c[0] = (float)cnt[0] * (1.0f / 8388608.0f);
    c[1] = (float)cnt[1] * (1.0f / 8388608.0f);
  }
}

// ================= fallback path (round-1 f32 kernels) =================

__global__ __launch_bounds__(256) void zero_r_kernel(float* __restrict__ r,
                                                     int* __restrict__ cnt) {
  int i = blockIdx.x * 256 + threadIdx.x;
  float4 z{0.f, 0.f, 0.f, 0.f};
  *(float4*)&r[(size_t)i * 4] = z;
  if (i == 0) { cnt[0] = 0; cnt[1] = 0; }
}

__global__ __launch_bounds__(256) void gemm_f32(
    const float* __restrict__ W, const float* __restrict__ X,
    float* __restrict__ Z, int M, int K) {
  const int T = 256;
  const int tt0 = blockIdx.x * 64;
  const int m0 = blockIdx.y * 128;
  const int b = blockIdx.z;
  const float* __restrict__ Xb = X + (size_t)b * K * T;
  float* __restrict__ Zb = Z + (size_t)b * M * T;
  __shared__ float Ws[16][132];
  __shared__ float Xs[16][68];
  const int tid = threadIdx.x;
  const int tx = tid & 15, ty = tid >> 4;
  const int ah = tid >> 1, ac = (tid & 1) * 8;
  const int bf = tid >> 4, btq = (tid & 15) * 4;
  float acc[8][4];
#pragma unroll
  for (int i = 0; i < 8; ++i)
#pragma unroll
    for (int j = 0; j < 4; ++j) acc[i][j] = 0.f;
  const float* wp = &W[(size_t)(m0 + ah) * K + ac];
  const float* xp = &Xb[(size_t)bf * T + tt0 + btq];
  for (int k0 = 0; k0 < K; k0 += 16) {
    float4 wa0 = *(const float4*)(wp + k0);
    float4 wa1 = *(const float4*)(wp + k0 + 4);
    float4 xv = *(const float4*)(xp + (size_t)k0 * T);
    __syncthreads();
    Ws[ac + 0][ah] = wa0.x; Ws[ac + 1][ah] = wa0.y;
    Ws[ac + 2][ah] = wa0.z; Ws[ac + 3][ah] = wa0.w;
    Ws[ac + 4][ah] = wa1.x; Ws[ac + 5][ah] = wa1.y;
    Ws[ac + 6][ah] = wa1.z; Ws[ac + 7][ah] = wa1.w;
    *(float4*)&Xs[bf][btq] = xv;
    __syncthreads();
#pragma unroll
    for (int f = 0; f < 16; ++f) {
      float4 a0 = *(const float4*)&Ws[f][ty * 8];
      float4 a1 = *(const float4*)&Ws[f][ty * 8 + 4];
      float4 xr = *(const float4*)&Xs[f][tx * 4];
      float av[8] = {a0.x, a0.y, a0.z, a0.w, a1.x, a1.y, a1.z, a1.w};
      float xw[4] = {xr.x, xr.y, xr.z, xr.w};
#pragma unroll
      for (int i = 0; i < 8; ++i)
#pragma unroll
        for (int j = 0; j < 4; ++j) acc[i][j] = fmaf(av[i], xw[j], acc[i][j]);
    }
  }
#pragma unroll
  for (int i = 0; i < 8; ++i) {
    float4 o{acc[i][0], acc[i][1], acc[i][2], acc[i][3]};
    *(float4*)&Zb[(size_t)(m0 + ty * 8 + i) * T + tt0 + tx * 4] = o;
  }
}

__global__ __launch_bounds__(256) void readout_kernel(
    const float* __restrict__ R1, const float* __restrict__ R2,
    const float* __restrict__ S1, const float* __restrict__ S2,
    float* __restrict__ O1, float* __restrict__ O2) {
  const int T = 256, K = 1024;
  const int tt0 = blockIdx.x * 64;
  const int kbeg = blockIdx.y * 256;
  const int zz = blockIdx.z;
  const int b = zz & 31;
  const float* __restrict__ R = (zz < 32) ? R1 : R2;
  const float* __restrict__ Sb = ((zz < 32) ? S1 : S2) + (size_t)b * K * T;
  float* __restrict__ Ob = ((zz < 32) ? O1 : O2) + (size_t)b * 128 * T;
  __shared__ float Ws[16][132];
  __shared__ float Xs[16][68];
  const int tid = threadIdx.x;
  const int tx = tid & 15, ty = tid >> 4;
  const int ah = tid >> 1, ac = (tid & 1) * 8;
  const int bf = tid >> 4, btq = (tid & 15) * 4;
  float acc[8][4];
#pragma unroll
  for (int i = 0; i < 8; ++i)
#pragma unroll
    for (int j = 0; j < 4; ++j) acc[i][j] = 0.f;
  const float* wp = &R[(size_t)ah * K + ac];
  const float* xp = &Sb[(size_t)bf * T + tt0 + btq];
  for (int k0 = kbeg; k0 < kbeg + 256; k0 += 16) {
    float4 wa0 = *(const float4*)(wp + k0);
    float4 wa1 = *(const float4*)(wp + k0 + 4);
    float4 xv = *(const float4*)(xp + (size_t)k0 * T);
    __syncthreads();
    Ws[ac + 0][ah] = wa0.x; Ws[ac + 1][ah] = wa0.y;
    Ws[ac + 2][ah] = wa0.z; Ws[ac + 3][ah] = wa0.w;
    Ws[ac + 4][ah] = wa1.x; Ws[ac + 5][ah] = wa1.y;
    Ws[ac + 6][ah] = wa1.z; Ws[ac + 7][ah] = wa1.w;
    *(float4*)&Xs[bf][btq] = xv;
    __syncthreads();
#pragma unroll
    for (int f = 0; f < 16; ++f) {
      float4 a0 = *(const float4*)&Ws[f][ty * 8];
      float4 a1 = *(const float4*)&Ws[f][ty * 8 + 4];
      float4 xr = *(const float4*)&Xs[f][tx * 4];
      float av[8] = {a0.x, a0.y, a0.z, a0.w, a1.x, a1.y, a1.z, a1.w};
      float xw[4] = {xr.x, xr.y, xr.z, xr.w};
#pragma unroll
      for (int i = 0; i < 8; ++i)
#pragma unroll
        for (int j = 0; j < 4; ++j) acc[i][j] = fmaf(av[i], xw[j], acc[i][j]);
    }
  }
#pragma unroll
  for (int i = 0; i < 8; ++i)
#pragma unroll
    for (int j = 0; j < 4; ++j)
      atomicAdd(&Ob[(size_t)(ty * 8 + i) * T + tt0 + tx * 4 + j], acc[i][j]);
}

// ================= launch =================
extern "C" void kernel_launch(void* const* d_in, const int* in_sizes, int n_in,
                              void* d_out, int out_size, void* d_ws, size_t ws_size,
                              hipStream_t stream) {
  const float* spike = (const float*)d_in[0];
  const float* W1 = (const float*)d_in[1];
  const float* W2 = (const float*)d_in[2];
  const float* R1 = (const float*)d_in[3];
  const float* R2 = (const float*)d_in[4];

  float* out = (float*)d_out;
  float* s1 = out;
  float* s2 = out + S_SZ;
  float* r1 = out + 2 * S_SZ;
  float* r2 = out + 2 * S_SZ + R_SZ;
  float* v1 = out + 2 * S_SZ + 2 * R_SZ;  // z1 then v1, in place
  float* v2 = out + 2 * S_SZ + 2 * R_SZ + S_SZ;
  float* cc = out + 4 * S_SZ + 2 * R_SZ;

  int* cnt = (int*)d_ws;
  unsigned short* w1s = (unsigned short*)((char*)d_ws + 64);  // 2 planes each
  unsigned short* w2s = w1s + 2 * 524288;
  unsigned short* r1s = w2s + 2 * 1048576;
  unsigned short* r2s = r1s + 2 * 131072;
  unsigned short* xT  = r2s + 2 * 131072;
  unsigned short* s1T = xT + 4194304;
  unsigned short* s2T = s1T + 8388608;
  const size_t WS_NEED = 48000000;  // 47.4 MB rounded up

  if (ws_size >= WS_NEED) {
    split_all_kernel<<<dim3(4096, 4), 256, 0, stream>>>(W1, W2, R1, R2, w1s, w2s,
                                                        r1s, r2s, cnt);
    tcvt_kernel<<<dim3(8, 4, 32), 256, 0, stream>>>(spike, xT, 512);
    gemm_mfma_lds<<<dim3(4, 8, 32), 256, 0, stream>>>(w1s, xT, v1, 1024, 512);
    scan_kernel<<<512, 64, 0, stream>>>(v1, s1, s1T, cnt + 0);
    gemm_mfma_lds<<<dim3(4, 8, 32), 256, 0, stream>>>(w2s, s1T, v2, 1024, 1024);
    scan_kernel<<<512, 64, 0, stream>>>(v2, s2, s2T, cnt + 1);
    readout_mfma_lds<<<dim3(8, 2, 32), 256, 0, stream>>>(r1s, r2s, s1T, s2T, r1,
                                                         r2, cnt, cc);
  } else {
    zero_r_kernel<<<2048, 256, 0, stream>>>(r1, cnt);
    gemm_f32<<<dim3(4, 8, 32), 256, 0, stream>>>(W1, spike, v1, 1024, 512);
    scan_kernel<<<512, 64, 0, stream>>>(v1, s1, nullptr, cnt + 0);
    gemm_f32<<<dim3(4, 8, 32), 256, 0, stream>>>(W2, s1, v2, 1024, 1024);
    scan_kernel<<<512, 64, 0, stream>>>(v2, s2, nullptr, cnt + 1);
    readout_kernel<<<dim3(4, 4, 64), 256, 0, stream>>>(R1, R2, s1, s2, r1, r2);
    finalize_kernel<<<1, 1, 0, stream>>>(cnt, cc);
  }
}